// Round 1
// baseline (185.648 us; speedup 1.0000x reference)
//
#include <hip/hip_runtime.h>
#include <cstdint>
#include <cstddef>

typedef __bf16 bf16_t;
typedef __bf16 bf16x4 __attribute__((ext_vector_type(4)));
typedef __bf16 bf16x8 __attribute__((ext_vector_type(8)));
typedef float f32x4 __attribute__((ext_vector_type(4)));

#define M_DIM 4096
#define K_DIM 2048
#define N_DIM 2048

// ---------------------------------------------------------------------------
// Pre-pass: transpose + convert a [K][N] f32 weight matrix to [N][K] bf16.
// 64x64 tiles via LDS (pad 65 to avoid bank conflicts).
// ---------------------------------------------------------------------------
__global__ __launch_bounds__(256) void transpose_to_bf16(
    const float* __restrict__ src, bf16_t* __restrict__ dst) {
  __shared__ float tile[64][65];
  const int t = threadIdx.x;
  const int k0 = blockIdx.y * 64;
  const int n0 = blockIdx.x * 64;
#pragma unroll
  for (int p = 0; p < 4; ++p) {
    const int r = p * 16 + (t >> 4);
    const int c = (t & 15) * 4;
    const float4 v = *reinterpret_cast<const float4*>(
        &src[(size_t)(k0 + r) * N_DIM + n0 + c]);
    tile[r][c + 0] = v.x;
    tile[r][c + 1] = v.y;
    tile[r][c + 2] = v.z;
    tile[r][c + 3] = v.w;
  }
  __syncthreads();
#pragma unroll
  for (int p = 0; p < 4; ++p) {
    const int n = p * 16 + (t >> 4);
    const int c = (t & 15) * 4;
    bf16x4 o;
    o[0] = (bf16_t)tile[c + 0][n];
    o[1] = (bf16_t)tile[c + 1][n];
    o[2] = (bf16_t)tile[c + 2][n];
    o[3] = (bf16_t)tile[c + 3][n];
    *reinterpret_cast<bf16x4*>(&dst[(size_t)(n0 + n) * K_DIM + k0 + c]) = o;
  }
}

// ---------------------------------------------------------------------------
// Fused LIF GEMM: acc = A1@W1 + A2@W2 (W* pre-transposed bf16 [N][K]),
// epilogue: next_I = a*I + acc; next_V = (b*V + next_I)*(1-Z);
//           next_Z = (next_V - 1 > 0).
// 128x128 tile, BK=32, 4 waves (2x2), each wave 64x64 via 4x4 mfma 16x16x32.
// ---------------------------------------------------------------------------
__global__ __launch_bounds__(256) void lif_fused_gemm(
    const float* __restrict__ A1, const float* __restrict__ A2,
    const bf16_t* __restrict__ W1, const bf16_t* __restrict__ W2,
    const float* __restrict__ Iin, const float* __restrict__ Vin,
    const float* __restrict__ Zin,
    float* __restrict__ outZ, float* __restrict__ outI,
    float* __restrict__ outV) {
  // pad 40 (80 B rows): 16B-aligned fragment reads, conflict-free slots
  __shared__ __align__(16) bf16_t As[128][40];
  __shared__ __align__(16) bf16_t Ws[128][40];

  const int tid = threadIdx.x;
  const int lane = tid & 63;
  const int wave = tid >> 6;
  const int wm = wave >> 1;  // 0..1
  const int wn = wave & 1;   // 0..1
  const int l15 = lane & 15;
  const int l4 = lane >> 4;
  const int m0 = blockIdx.y * 128;
  const int n0 = blockIdx.x * 128;

  f32x4 acc[4][4];
#pragma unroll
  for (int i = 0; i < 4; ++i)
#pragma unroll
    for (int j = 0; j < 4; ++j)
#pragma unroll
      for (int e = 0; e < 4; ++e) acc[i][j][e] = 0.0f;

  const int ar = tid >> 3;        // A stage: row group 0..31
  const int ac = (tid & 7) * 4;   // A stage: 4-float col 0..28
  const int wr = tid >> 2;        // W stage: row group 0..63
  const int wc = (tid & 3) * 8;   // W stage: 8-bf16 col 0..24

  for (int h = 0; h < 2; ++h) {
    const float* __restrict__ Ap = h ? A2 : A1;
    const bf16_t* __restrict__ Wp = h ? W2 : W1;
    for (int kb = 0; kb < K_DIM / 32; ++kb) {
      const int k0 = kb * 32;
      // ---- stage A tile: 128x32 f32 -> bf16 LDS ----
#pragma unroll
      for (int p = 0; p < 4; ++p) {
        const int row = p * 32 + ar;
        const float4 v = *reinterpret_cast<const float4*>(
            &Ap[(size_t)(m0 + row) * K_DIM + k0 + ac]);
        bf16x4 o;
        o[0] = (bf16_t)v.x;
        o[1] = (bf16_t)v.y;
        o[2] = (bf16_t)v.z;
        o[3] = (bf16_t)v.w;
        *reinterpret_cast<bf16x4*>(&As[row][ac]) = o;
      }
      // ---- stage W tile: 128 n-rows x 32 k (bf16, already transposed) ----
#pragma unroll
      for (int p = 0; p < 2; ++p) {
        const int row = p * 64 + wr;
        *reinterpret_cast<bf16x8*>(&Ws[row][wc]) =
            *reinterpret_cast<const bf16x8*>(
                &Wp[(size_t)(n0 + row) * K_DIM + k0 + wc]);
      }
      __syncthreads();

      bf16x8 af[4], bfr[4];
#pragma unroll
      for (int i = 0; i < 4; ++i) {
        af[i] = *reinterpret_cast<const bf16x8*>(
            &As[wm * 64 + i * 16 + l15][l4 * 8]);
        bfr[i] = *reinterpret_cast<const bf16x8*>(
            &Ws[wn * 64 + i * 16 + l15][l4 * 8]);
      }
#pragma unroll
      for (int mi = 0; mi < 4; ++mi)
#pragma unroll
        for (int ni = 0; ni < 4; ++ni)
          acc[mi][ni] = __builtin_amdgcn_mfma_f32_16x16x32_bf16(
              af[mi], bfr[ni], acc[mi][ni], 0, 0, 0);
      __syncthreads();
    }
  }

  // ---- fused LIF epilogue ----
  const float alpha = 0.90483741803595957f;  // exp(-0.1)
  const float beta = 0.81873075307798182f;   // exp(-0.2)
#pragma unroll
  for (int mi = 0; mi < 4; ++mi) {
#pragma unroll
    for (int j = 0; j < 4; ++j) {
      const int r = m0 + wm * 64 + mi * 16 + l4 * 4 + j;
#pragma unroll
      for (int ni = 0; ni < 4; ++ni) {
        const int c = n0 + wn * 64 + ni * 16 + l15;
        const size_t idx = (size_t)r * N_DIM + c;
        const float zin = Zin[idx];
        const float nI = alpha * Iin[idx] + acc[mi][ni][j];
        const float nV = (beta * Vin[idx] + nI) * (1.0f - zin);
        outI[idx] = nI;
        outV[idx] = nV;
        outZ[idx] = (nV > 1.0f) ? 1.0f : 0.0f;
      }
    }
  }
}

extern "C" void kernel_launch(void* const* d_in, const int* in_sizes, int n_in,
                              void* d_out, int out_size, void* d_ws,
                              size_t ws_size, hipStream_t stream) {
  const float* inputs = (const float*)d_in[0];
  const float* I = (const float*)d_in[1];
  const float* V = (const float*)d_in[2];
  const float* Z = (const float*)d_in[3];
  const float* fwd_w = (const float*)d_in[4];
  const float* rec_w = (const float*)d_in[5];

  bf16_t* w1t = (bf16_t*)d_ws;                       // 8 MiB
  bf16_t* w2t = w1t + (size_t)K_DIM * N_DIM;         // 8 MiB
  float* outZ = (float*)d_out;
  float* outI = outZ + (size_t)M_DIM * N_DIM;
  float* outV = outI + (size_t)M_DIM * N_DIM;

  dim3 tgrid(N_DIM / 64, K_DIM / 64);
  hipLaunchKernelGGL(transpose_to_bf16, tgrid, dim3(256), 0, stream, fwd_w,
                     w1t);
  hipLaunchKernelGGL(transpose_to_bf16, tgrid, dim3(256), 0, stream, rec_w,
                     w2t);

  dim3 ggrid(N_DIM / 128, M_DIM / 128);
  hipLaunchKernelGGL(lif_fused_gemm, ggrid, dim3(256), 0, stream, inputs, Z,
                     w1t, w2t, I, V, Z, outZ, outI, outV);
}

// Round 2
// 151.923 us; speedup vs baseline: 1.2220x; 1.2220x over previous
//
#include <hip/hip_runtime.h>
#include <cstdint>
#include <cstddef>

typedef __bf16 bf16_t;
typedef __bf16 bf16x4 __attribute__((ext_vector_type(4)));
typedef __bf16 bf16x8 __attribute__((ext_vector_type(8)));
typedef float f32x4 __attribute__((ext_vector_type(4)));

#define M_DIM 4096
#define K_DIM 2048
#define N_DIM 2048
#define KCAT 4096  // fused K: [inputs | Z] and [fwd_w ; rec_w]

// async global->LDS, 16B per lane (LDS dest = wave-uniform base + lane*16)
__device__ __forceinline__ void gload_lds16(const bf16_t* g, bf16_t* l) {
  __builtin_amdgcn_global_load_lds(
      (const __attribute__((address_space(1))) void*)g,
      (__attribute__((address_space(3))) void*)l, 16, 0, 0);
}

// ---------------------------------------------------------------------------
// Prepass 1: convert inputs (half 0) and Z (half 1) f32 -> bf16 into
// A_cat [M][KCAT], k-contiguous. 8 elems/thread, fully coalesced.
// ---------------------------------------------------------------------------
__global__ __launch_bounds__(256) void convert_acat(
    const float* __restrict__ inputs, const float* __restrict__ Z,
    bf16_t* __restrict__ acat) {
  const int g = blockIdx.x * 256 + threadIdx.x;
  const int half = g >> 20;          // 2^20 threads per half
  const int i = g & 1048575;
  const int m = i >> 8;              // 256 threads per 2048-col row
  const int kc = (i & 255) * 8;
  const float* src = (half ? Z : inputs) + (size_t)m * K_DIM + kc;
  const float4 v0 = *reinterpret_cast<const float4*>(src);
  const float4 v1 = *reinterpret_cast<const float4*>(src + 4);
  bf16x8 o;
  o[0] = (bf16_t)v0.x; o[1] = (bf16_t)v0.y;
  o[2] = (bf16_t)v0.z; o[3] = (bf16_t)v0.w;
  o[4] = (bf16_t)v1.x; o[5] = (bf16_t)v1.y;
  o[6] = (bf16_t)v1.z; o[7] = (bf16_t)v1.w;
  *reinterpret_cast<bf16x8*>(
      &acat[(size_t)m * KCAT + (size_t)half * K_DIM + kc]) = o;
}

// ---------------------------------------------------------------------------
// Prepass 2: transpose+convert [K][N] f32 weights -> W_cat^T [N][KCAT] bf16.
// blockIdx.z selects fwd_w (k cols 0..2047) vs rec_w (k cols 2048..4095).
// ---------------------------------------------------------------------------
__global__ __launch_bounds__(256) void transpose_wcat(
    const float* __restrict__ w1, const float* __restrict__ w2,
    bf16_t* __restrict__ wcat) {
  __shared__ float tile[64][65];
  const int t = threadIdx.x;
  const int half = blockIdx.z;
  const float* __restrict__ src = half ? w2 : w1;
  const int k0 = blockIdx.y * 64;
  const int n0 = blockIdx.x * 64;
#pragma unroll
  for (int p = 0; p < 4; ++p) {
    const int r = p * 16 + (t >> 4);
    const int c = (t & 15) * 4;
    const float4 v = *reinterpret_cast<const float4*>(
        &src[(size_t)(k0 + r) * N_DIM + n0 + c]);
    tile[r][c + 0] = v.x;
    tile[r][c + 1] = v.y;
    tile[r][c + 2] = v.z;
    tile[r][c + 3] = v.w;
  }
  __syncthreads();
#pragma unroll
  for (int p = 0; p < 4; ++p) {
    const int n = p * 16 + (t >> 4);
    const int c = (t & 15) * 4;
    bf16x4 o;
    o[0] = (bf16_t)tile[c + 0][n];
    o[1] = (bf16_t)tile[c + 1][n];
    o[2] = (bf16_t)tile[c + 2][n];
    o[3] = (bf16_t)tile[c + 3][n];
    *reinterpret_cast<bf16x4*>(
        &wcat[(size_t)(n0 + n) * KCAT + (size_t)half * K_DIM + k0 + c]) = o;
  }
}

// ---------------------------------------------------------------------------
// Main fused GEMM (m97 structure): C = A_cat @ W_cat^T, 128x128 tile, BK=32,
// single-buffered LDS staged via global_load_lds width=16, 4 waves (2x2),
// each wave 64x64 via 4x4 mfma_f32_16x16x32_bf16. Fused LIF epilogue.
// ---------------------------------------------------------------------------
__global__ __launch_bounds__(256) void lif_gemm_gl(
    const bf16_t* __restrict__ A, const bf16_t* __restrict__ W,
    const float* __restrict__ Iin, const float* __restrict__ Vin,
    const float* __restrict__ Zin,
    float* __restrict__ outZ, float* __restrict__ outI,
    float* __restrict__ outV) {
  __shared__ __align__(16) bf16_t As[128 * 32];  // linear [128][32]
  __shared__ __align__(16) bf16_t Ws[128 * 32];

  const int tid = threadIdx.x;
  const int lane = tid & 63;
  const int wave = tid >> 6;
  const int wm = wave >> 1;  // 0..1
  const int wn = wave & 1;   // 0..1
  const int l15 = lane & 15;
  const int l4 = lane >> 4;
  const int m0 = blockIdx.y * 128;
  const int n0 = blockIdx.x * 128;

  // staging map: slot = p*256+tid covers LDS row slot/4, col (slot%4)*8
  const int sr = tid >> 2;         // 0..63
  const int sc = (tid & 3) * 8;    // 0,8,16,24
  const bf16_t* aG0 = A + (size_t)(m0 + sr) * KCAT + sc;
  const bf16_t* aG1 = A + (size_t)(m0 + 64 + sr) * KCAT + sc;
  const bf16_t* wG0 = W + (size_t)(n0 + sr) * KCAT + sc;
  const bf16_t* wG1 = W + (size_t)(n0 + 64 + sr) * KCAT + sc;
  bf16_t* aL0 = &As[tid * 8];
  bf16_t* aL1 = &As[2048 + tid * 8];
  bf16_t* wL0 = &Ws[tid * 8];
  bf16_t* wL1 = &Ws[2048 + tid * 8];

  f32x4 acc[4][4];
#pragma unroll
  for (int i = 0; i < 4; ++i)
#pragma unroll
    for (int j = 0; j < 4; ++j)
#pragma unroll
      for (int e = 0; e < 4; ++e) acc[i][j][e] = 0.0f;

  for (int kb = 0; kb < KCAT / 32; ++kb) {
    gload_lds16(aG0, aL0);
    gload_lds16(aG1, aL1);
    gload_lds16(wG0, wL0);
    gload_lds16(wG1, wL1);
    aG0 += 32; aG1 += 32; wG0 += 32; wG1 += 32;
    __syncthreads();  // compiler drains vmcnt before barrier

    bf16x8 af[4], bfr[4];
#pragma unroll
    for (int i = 0; i < 4; ++i) {
      af[i] = *reinterpret_cast<const bf16x8*>(
          &As[(wm * 64 + i * 16 + l15) * 32 + l4 * 8]);
      bfr[i] = *reinterpret_cast<const bf16x8*>(
          &Ws[(wn * 64 + i * 16 + l15) * 32 + l4 * 8]);
    }
#pragma unroll
    for (int mi = 0; mi < 4; ++mi)
#pragma unroll
      for (int ni = 0; ni < 4; ++ni)
        acc[mi][ni] = __builtin_amdgcn_mfma_f32_16x16x32_bf16(
            af[mi], bfr[ni], acc[mi][ni], 0, 0, 0);
    __syncthreads();
  }

  // ---- fused LIF epilogue (verified in round 1) ----
  const float alpha = 0.90483741803595957f;  // exp(-0.1)
  const float beta = 0.81873075307798182f;   // exp(-0.2)
#pragma unroll
  for (int mi = 0; mi < 4; ++mi) {
#pragma unroll
    for (int j = 0; j < 4; ++j) {
      const int r = m0 + wm * 64 + mi * 16 + l4 * 4 + j;
#pragma unroll
      for (int ni = 0; ni < 4; ++ni) {
        const int c = n0 + wn * 64 + ni * 16 + l15;
        const size_t idx = (size_t)r * N_DIM + c;
        const float zin = Zin[idx];
        const float nI = alpha * Iin[idx] + acc[mi][ni][j];
        const float nV = (beta * Vin[idx] + nI) * (1.0f - zin);
        outI[idx] = nI;
        outV[idx] = nV;
        outZ[idx] = (nV > 1.0f) ? 1.0f : 0.0f;
      }
    }
  }
}

// ===========================================================================
// Round-1 fallback path (used only if ws_size < 48 MiB)
// ===========================================================================
__global__ __launch_bounds__(256) void transpose_to_bf16(
    const float* __restrict__ src, bf16_t* __restrict__ dst) {
  __shared__ float tile[64][65];
  const int t = threadIdx.x;
  const int k0 = blockIdx.y * 64;
  const int n0 = blockIdx.x * 64;
#pragma unroll
  for (int p = 0; p < 4; ++p) {
    const int r = p * 16 + (t >> 4);
    const int c = (t & 15) * 4;
    const float4 v = *reinterpret_cast<const float4*>(
        &src[(size_t)(k0 + r) * N_DIM + n0 + c]);
    tile[r][c + 0] = v.x;
    tile[r][c + 1] = v.y;
    tile[r][c + 2] = v.z;
    tile[r][c + 3] = v.w;
  }
  __syncthreads();
#pragma unroll
  for (int p = 0; p < 4; ++p) {
    const int n = p * 16 + (t >> 4);
    const int c = (t & 15) * 4;
    bf16x4 o;
    o[0] = (bf16_t)tile[c + 0][n];
    o[1] = (bf16_t)tile[c + 1][n];
    o[2] = (bf16_t)tile[c + 2][n];
    o[3] = (bf16_t)tile[c + 3][n];
    *reinterpret_cast<bf16x4*>(&dst[(size_t)(n0 + n) * K_DIM + k0 + c]) = o;
  }
}

__global__ __launch_bounds__(256) void lif_fused_gemm(
    const float* __restrict__ A1, const float* __restrict__ A2,
    const bf16_t* __restrict__ W1, const bf16_t* __restrict__ W2,
    const float* __restrict__ Iin, const float* __restrict__ Vin,
    const float* __restrict__ Zin,
    float* __restrict__ outZ, float* __restrict__ outI,
    float* __restrict__ outV) {
  __shared__ __align__(16) bf16_t As[128][40];
  __shared__ __align__(16) bf16_t Ws[128][40];

  const int tid = threadIdx.x;
  const int lane = tid & 63;
  const int wave = tid >> 6;
  const int wm = wave >> 1;
  const int wn = wave & 1;
  const int l15 = lane & 15;
  const int l4 = lane >> 4;
  const int m0 = blockIdx.y * 128;
  const int n0 = blockIdx.x * 128;

  f32x4 acc[4][4];
#pragma unroll
  for (int i = 0; i < 4; ++i)
#pragma unroll
    for (int j = 0; j < 4; ++j)
#pragma unroll
      for (int e = 0; e < 4; ++e) acc[i][j][e] = 0.0f;

  const int ar = tid >> 3;
  const int ac = (tid & 7) * 4;
  const int wr = tid >> 2;
  const int wc = (tid & 3) * 8;

  for (int h = 0; h < 2; ++h) {
    const float* __restrict__ Ap = h ? A2 : A1;
    const bf16_t* __restrict__ Wp = h ? W2 : W1;
    for (int kb = 0; kb < K_DIM / 32; ++kb) {
      const int k0 = kb * 32;
#pragma unroll
      for (int p = 0; p < 4; ++p) {
        const int row = p * 32 + ar;
        const float4 v = *reinterpret_cast<const float4*>(
            &Ap[(size_t)(m0 + row) * K_DIM + k0 + ac]);
        bf16x4 o;
        o[0] = (bf16_t)v.x;
        o[1] = (bf16_t)v.y;
        o[2] = (bf16_t)v.z;
        o[3] = (bf16_t)v.w;
        *reinterpret_cast<bf16x4*>(&As[row][ac]) = o;
      }
#pragma unroll
      for (int p = 0; p < 2; ++p) {
        const int row = p * 64 + wr;
        *reinterpret_cast<bf16x8*>(&Ws[row][wc]) =
            *reinterpret_cast<const bf16x8*>(
                &Wp[(size_t)(n0 + row) * K_DIM + k0 + wc]);
      }
      __syncthreads();

      bf16x8 af[4], bfr[4];
#pragma unroll
      for (int i = 0; i < 4; ++i) {
        af[i] = *reinterpret_cast<const bf16x8*>(
            &As[wm * 64 + i * 16 + l15][l4 * 8]);
        bfr[i] = *reinterpret_cast<const bf16x8*>(
            &Ws[wn * 64 + i * 16 + l15][l4 * 8]);
      }
#pragma unroll
      for (int mi = 0; mi < 4; ++mi)
#pragma unroll
        for (int ni = 0; ni < 4; ++ni)
          acc[mi][ni] = __builtin_amdgcn_mfma_f32_16x16x32_bf16(
              af[mi], bfr[ni], acc[mi][ni], 0, 0, 0);
      __syncthreads();
    }
  }

  const float alpha = 0.90483741803595957f;
  const float beta = 0.81873075307798182f;
#pragma unroll
  for (int mi = 0; mi < 4; ++mi) {
#pragma unroll
    for (int j = 0; j < 4; ++j) {
      const int r = m0 + wm * 64 + mi * 16 + l4 * 4 + j;
#pragma unroll
      for (int ni = 0; ni < 4; ++ni) {
        const int c = n0 + wn * 64 + ni * 16 + l15;
        const size_t idx = (size_t)r * N_DIM + c;
        const float zin = Zin[idx];
        const float nI = alpha * Iin[idx] + acc[mi][ni][j];
        const float nV = (beta * Vin[idx] + nI) * (1.0f - zin);
        outI[idx] = nI;
        outV[idx] = nV;
        outZ[idx] = (nV > 1.0f) ? 1.0f : 0.0f;
      }
    }
  }
}

extern "C" void kernel_launch(void* const* d_in, const int* in_sizes, int n_in,
                              void* d_out, int out_size, void* d_ws,
                              size_t ws_size, hipStream_t stream) {
  const float* inputs = (const float*)d_in[0];
  const float* I = (const float*)d_in[1];
  const float* V = (const float*)d_in[2];
  const float* Z = (const float*)d_in[3];
  const float* fwd_w = (const float*)d_in[4];
  const float* rec_w = (const float*)d_in[5];

  float* outZ = (float*)d_out;
  float* outI = outZ + (size_t)M_DIM * N_DIM;
  float* outV = outI + (size_t)M_DIM * N_DIM;

  const size_t ACAT_BYTES = (size_t)M_DIM * KCAT * sizeof(bf16_t);  // 32 MiB
  const size_t WCAT_BYTES = (size_t)N_DIM * KCAT * sizeof(bf16_t);  // 16 MiB

  if (ws_size >= ACAT_BYTES + WCAT_BYTES) {
    bf16_t* acat = (bf16_t*)d_ws;
    bf16_t* wcat = (bf16_t*)((char*)d_ws + ACAT_BYTES);

    hipLaunchKernelGGL(convert_acat, dim3(8192), dim3(256), 0, stream, inputs,
                       Z, acat);
    hipLaunchKernelGGL(transpose_wcat, dim3(N_DIM / 64, K_DIM / 64, 2),
                       dim3(256), 0, stream, fwd_w, rec_w, wcat);
    hipLaunchKernelGGL(lif_gemm_gl, dim3(N_DIM / 128, M_DIM / 128), dim3(256),
                       0, stream, acat, wcat, I, V, Z, outZ, outI, outV);
  } else {
    // fallback: round-1 path (16 MiB workspace)
    bf16_t* w1t = (bf16_t*)d_ws;
    bf16_t* w2t = w1t + (size_t)K_DIM * N_DIM;
    dim3 tgrid(N_DIM / 64, K_DIM / 64);
    hipLaunchKernelGGL(transpose_to_bf16, tgrid, dim3(256), 0, stream, fwd_w,
                       w1t);
    hipLaunchKernelGGL(transpose_to_bf16, tgrid, dim3(256), 0, stream, rec_w,
                       w2t);
    dim3 ggrid(N_DIM / 128, M_DIM / 128);
    hipLaunchKernelGGL(lif_fused_gemm, ggrid, dim3(256), 0, stream, inputs, Z,
                       w1t, w2t, I, V, Z, outZ, outI, outV);
  }
}

// Round 3
// 132.950 us; speedup vs baseline: 1.3964x; 1.1427x over previous
//
#include <hip/hip_runtime.h>
#include <cstdint>
#include <cstddef>

typedef __bf16 bf16_t;
typedef __bf16 bf16x4 __attribute__((ext_vector_type(4)));
typedef __bf16 bf16x8 __attribute__((ext_vector_type(8)));
typedef float f32x4 __attribute__((ext_vector_type(4)));

#define M_DIM 4096
#define K_DIM 2048
#define N_DIM 2048
#define KCAT 4096  // fused K: [inputs | Z] and [fwd_w ; rec_w]

// ---- 8-phase GEMM geometry ----
#define BM 256
#define BN 128
#define BK 64
#define NT (KCAT / BK)                // 64 K-tiles
#define A_ELEMS (BM * BK)             // 16384 bf16
#define B_ELEMS (BN * BK)             // 8192 bf16
#define PER_BUF (A_ELEMS + B_ELEMS)   // 24576 bf16 = 49152 B
#define B_OFF A_ELEMS
#define LDS_BYTES (3 * PER_BUF * 2)   // 147456 B (3 buffers)

#define MFMA16(a, b, c) \
  __builtin_amdgcn_mfma_f32_16x16x32_bf16((a), (b), (c), 0, 0, 0)

// async global->LDS, 16B/lane (LDS dest = wave-uniform base + lane*16)
__device__ __forceinline__ void gload_lds16(const bf16_t* g, bf16_t* l) {
  __builtin_amdgcn_global_load_lds(
      (const __attribute__((address_space(1))) void*)g,
      (__attribute__((address_space(3))) void*)l, 16, 0, 0);
}

// ---------------------------------------------------------------------------
// Prepass 1: f32 -> bf16, A_cat [M][KCAT] = [inputs | Z], k-contiguous.
// ---------------------------------------------------------------------------
__global__ __launch_bounds__(256) void convert_acat(
    const float* __restrict__ inputs, const float* __restrict__ Z,
    bf16_t* __restrict__ acat) {
  const int g = blockIdx.x * 256 + threadIdx.x;
  const int half = g >> 20;
  const int i = g & 1048575;
  const int m = i >> 8;
  const int kc = (i & 255) * 8;
  const float* src = (half ? Z : inputs) + (size_t)m * K_DIM + kc;
  const float4 v0 = *reinterpret_cast<const float4*>(src);
  const float4 v1 = *reinterpret_cast<const float4*>(src + 4);
  bf16x8 o;
  o[0] = (bf16_t)v0.x; o[1] = (bf16_t)v0.y;
  o[2] = (bf16_t)v0.z; o[3] = (bf16_t)v0.w;
  o[4] = (bf16_t)v1.x; o[5] = (bf16_t)v1.y;
  o[6] = (bf16_t)v1.z; o[7] = (bf16_t)v1.w;
  *reinterpret_cast<bf16x8*>(
      &acat[(size_t)m * KCAT + (size_t)half * K_DIM + kc]) = o;
}

// ---------------------------------------------------------------------------
// Prepass 2: transpose+convert [K][N] f32 weights -> W_cat^T [N][KCAT] bf16.
// ---------------------------------------------------------------------------
__global__ __launch_bounds__(256) void transpose_wcat(
    const float* __restrict__ w1, const float* __restrict__ w2,
    bf16_t* __restrict__ wcat) {
  __shared__ float tile[64][65];
  const int t = threadIdx.x;
  const int half = blockIdx.z;
  const float* __restrict__ src = half ? w2 : w1;
  const int k0 = blockIdx.y * 64;
  const int n0 = blockIdx.x * 64;
#pragma unroll
  for (int p = 0; p < 4; ++p) {
    const int r = p * 16 + (t >> 4);
    const int c = (t & 15) * 4;
    const float4 v = *reinterpret_cast<const float4*>(
        &src[(size_t)(k0 + r) * N_DIM + n0 + c]);
    tile[r][c + 0] = v.x;
    tile[r][c + 1] = v.y;
    tile[r][c + 2] = v.z;
    tile[r][c + 3] = v.w;
  }
  __syncthreads();
#pragma unroll
  for (int p = 0; p < 4; ++p) {
    const int n = p * 16 + (t >> 4);
    const int c = (t & 15) * 4;
    bf16x4 o;
    o[0] = (bf16_t)tile[c + 0][n];
    o[1] = (bf16_t)tile[c + 1][n];
    o[2] = (bf16_t)tile[c + 2][n];
    o[3] = (bf16_t)tile[c + 3][n];
    *reinterpret_cast<bf16x4*>(
        &wcat[(size_t)(n0 + n) * KCAT + (size_t)half * K_DIM + k0 + c]) = o;
  }
}

// ---------------------------------------------------------------------------
// Main GEMM, deep-pipelined (T2 swizzle + T3/T4 counted vmcnt + T5 setprio):
// BM=256 x BN=128, BK=64, 512 threads (8 waves, 4M x 2N, 64x64/wave),
// 3 LDS buffers, prefetch depth 2, vmcnt(6) once per K-tile.
// LDS layout per buffer: A [256 rows][8 slots of 16B], slot swizzled by
// phys = logical ^ (row & 7); staged via pre-swizzled GLOBAL source so the
// global_load_lds LDS dest stays linear (rule 21).
// ---------------------------------------------------------------------------
__global__ __launch_bounds__(512, 2) void lif_gemm_8p(
    const bf16_t* __restrict__ A, const bf16_t* __restrict__ W,
    const float* __restrict__ Iin, const float* __restrict__ Vin,
    const float* __restrict__ Zin,
    float* __restrict__ outZ, float* __restrict__ outI,
    float* __restrict__ outV) {
  extern __shared__ __align__(16) bf16_t lds[];

  const int tid = threadIdx.x;
  const int lane = tid & 63;
  const int wave = tid >> 6;   // 0..7
  const int wm = wave >> 1;    // 0..3 (M quarter)
  const int wn = wave & 1;     // 0..1 (N half)
  const int l15 = lane & 15;
  const int l4 = lane >> 4;

  // T1: XCD-aware block swizzle (256 blocks, 256 % 8 == 0 -> bijective)
  const int bid = blockIdx.x;
  const int swz = (bid & 7) * 32 + (bid >> 3);
  const int m0 = (swz >> 4) * BM;  // 16 m-tiles
  const int n0 = (swz & 15) * BN;  // 16 n-tiles

  // ---- staging addresses (pre-swizzled global source, linear LDS dest) ----
  const int lr = lane >> 3;              // sub-row 0..7 within a wave-load
  const int sg = (lane & 7) ^ lr;        // swizzled logical 16B-slot
  const bf16_t* aSrc[4];
  const bf16_t* bSrc[2];
  int aDst[4], bDst[2];
#pragma unroll
  for (int i = 0; i < 4; ++i) {
    const int r = wave * 32 + i * 8 + lr;  // A rows: wave*32 .. +31
    aSrc[i] = A + (size_t)(m0 + r) * KCAT + sg * 8;
    aDst[i] = r * BK + (lane & 7) * 8;     // linear: wavebase + lane*16B
  }
#pragma unroll
  for (int i = 0; i < 2; ++i) {
    const int r = wave * 16 + i * 8 + lr;  // B rows: wave*16 .. +15
    bSrc[i] = W + (size_t)(n0 + r) * KCAT + sg * 8;
    bDst[i] = B_OFF + r * BK + (lane & 7) * 8;
  }

  // ---- fragment read offsets (swizzled), relative to buffer base ----
  int aOff[4][2], bOff[4][2];
#pragma unroll
  for (int mi = 0; mi < 4; ++mi)
#pragma unroll
    for (int ks = 0; ks < 2; ++ks) {
      const int row = wm * 64 + mi * 16 + l15;
      const int phys = (l4 + ks * 4) ^ (l15 & 7);
      aOff[mi][ks] = row * BK + phys * 8;
    }
#pragma unroll
  for (int ni = 0; ni < 4; ++ni)
#pragma unroll
    for (int ks = 0; ks < 2; ++ks) {
      const int row = wn * 64 + ni * 16 + l15;
      const int phys = (l4 + ks * 4) ^ (l15 & 7);
      bOff[ni][ks] = B_OFF + row * BK + phys * 8;
    }

  f32x4 acc[4][4];
#pragma unroll
  for (int i = 0; i < 4; ++i)
#pragma unroll
    for (int j = 0; j < 4; ++j)
#pragma unroll
      for (int e = 0; e < 4; ++e) acc[i][j][e] = 0.0f;

  // ---- prologue: stage tile 0 -> buf0, tile 1 -> buf1 ----
#pragma unroll
  for (int i = 0; i < 4; ++i) gload_lds16(aSrc[i], lds + aDst[i]);
#pragma unroll
  for (int i = 0; i < 2; ++i) gload_lds16(bSrc[i], lds + bDst[i]);
#pragma unroll
  for (int i = 0; i < 4; ++i)
    gload_lds16(aSrc[i] + BK, lds + PER_BUF + aDst[i]);
#pragma unroll
  for (int i = 0; i < 2; ++i)
    gload_lds16(bSrc[i] + BK, lds + PER_BUF + bDst[i]);
  __builtin_amdgcn_sched_barrier(0);
  asm volatile("s_waitcnt vmcnt(6)" ::: "memory");  // tile 0 landed
  __builtin_amdgcn_sched_barrier(0);
  __builtin_amdgcn_s_barrier();
  __builtin_amdgcn_sched_barrier(0);

  int cur = 0;
  for (int t = 0; t < NT; ++t) {
    const int nxt = (cur == 0) ? 2 : cur - 1;  // (t+2) % 3
    bf16_t* bufC = lds + cur * PER_BUF;
    bf16_t* bufN = lds + nxt * PER_BUF;
    const bool doStage = (t + 2 < NT);
    const int ktN = (t + 2) * BK;

    // ================= phase 0: stage part 1; read; MFMA ni=0,1 ==========
    if (doStage) {
      gload_lds16(aSrc[0] + ktN, bufN + aDst[0]);
      gload_lds16(aSrc[1] + ktN, bufN + aDst[1]);
      gload_lds16(bSrc[0] + ktN, bufN + bDst[0]);
    }
    bf16x8 a[4][2], b0[2][2];
#pragma unroll
    for (int mi = 0; mi < 4; ++mi)
#pragma unroll
      for (int ks = 0; ks < 2; ++ks)
        a[mi][ks] = *reinterpret_cast<const bf16x8*>(bufC + aOff[mi][ks]);
#pragma unroll
    for (int ni = 0; ni < 2; ++ni)
#pragma unroll
      for (int ks = 0; ks < 2; ++ks)
        b0[ni][ks] = *reinterpret_cast<const bf16x8*>(bufC + bOff[ni][ks]);
    __builtin_amdgcn_sched_barrier(0);
    __builtin_amdgcn_s_barrier();
    __builtin_amdgcn_s_setprio(1);
#pragma unroll
    for (int mi = 0; mi < 4; ++mi)
#pragma unroll
      for (int ni = 0; ni < 2; ++ni) {
        acc[mi][ni] = MFMA16(a[mi][0], b0[ni][0], acc[mi][ni]);
        acc[mi][ni] = MFMA16(a[mi][1], b0[ni][1], acc[mi][ni]);
      }
    __builtin_amdgcn_s_setprio(0);
    __builtin_amdgcn_sched_barrier(0);
    __builtin_amdgcn_s_barrier();
    __builtin_amdgcn_sched_barrier(0);

    // ================= phase 1: stage part 2; read; MFMA ni=2,3 ==========
    if (doStage) {
      gload_lds16(aSrc[2] + ktN, bufN + aDst[2]);
      gload_lds16(aSrc[3] + ktN, bufN + aDst[3]);
      gload_lds16(bSrc[1] + ktN, bufN + bDst[1]);
    }
    bf16x8 b1[2][2];
#pragma unroll
    for (int ni = 0; ni < 2; ++ni)
#pragma unroll
      for (int ks = 0; ks < 2; ++ks)
        b1[ni][ks] = *reinterpret_cast<const bf16x8*>(bufC + bOff[2 + ni][ks]);
    __builtin_amdgcn_sched_barrier(0);
    __builtin_amdgcn_s_barrier();
    __builtin_amdgcn_s_setprio(1);
#pragma unroll
    for (int mi = 0; mi < 4; ++mi)
#pragma unroll
      for (int ni = 0; ni < 2; ++ni) {
        acc[mi][2 + ni] = MFMA16(a[mi][0], b1[ni][0], acc[mi][2 + ni]);
        acc[mi][2 + ni] = MFMA16(a[mi][1], b1[ni][1], acc[mi][2 + ni]);
      }
    __builtin_amdgcn_s_setprio(0);
    // counted vmcnt (T4): keep next tile's 6 loads in flight, drain only at tail
    __builtin_amdgcn_sched_barrier(0);
    if (doStage) {
      asm volatile("s_waitcnt vmcnt(6)" ::: "memory");
    } else {
      asm volatile("s_waitcnt vmcnt(0)" ::: "memory");
    }
    __builtin_amdgcn_sched_barrier(0);
    __builtin_amdgcn_s_barrier();
    __builtin_amdgcn_sched_barrier(0);

    cur = (cur == 2) ? 0 : cur + 1;
  }

  // ---- fused LIF epilogue (layout verified rounds 1-2) ----
  const float alpha = 0.90483741803595957f;  // exp(-0.1)
  const float beta = 0.81873075307798182f;   // exp(-0.2)
#pragma unroll
  for (int mi = 0; mi < 4; ++mi) {
#pragma unroll
    for (int j = 0; j < 4; ++j) {
      const int r = m0 + wm * 64 + mi * 16 + l4 * 4 + j;
#pragma unroll
      for (int ni = 0; ni < 4; ++ni) {
        const int c = n0 + wn * 64 + ni * 16 + l15;
        const size_t idx = (size_t)r * N_DIM + c;
        const float zin = Zin[idx];
        const float nI = alpha * Iin[idx] + acc[mi][ni][j];
        const float nV = (beta * Vin[idx] + nI) * (1.0f - zin);
        outI[idx] = nI;
        outV[idx] = nV;
        outZ[idx] = (nV > 1.0f) ? 1.0f : 0.0f;
      }
    }
  }
}

extern "C" void kernel_launch(void* const* d_in, const int* in_sizes, int n_in,
                              void* d_out, int out_size, void* d_ws,
                              size_t ws_size, hipStream_t stream) {
  const float* inputs = (const float*)d_in[0];
  const float* I = (const float*)d_in[1];
  const float* V = (const float*)d_in[2];
  const float* Z = (const float*)d_in[3];
  const float* fwd_w = (const float*)d_in[4];
  const float* rec_w = (const float*)d_in[5];

  float* outZ = (float*)d_out;
  float* outI = outZ + (size_t)M_DIM * N_DIM;
  float* outV = outI + (size_t)M_DIM * N_DIM;

  const size_t ACAT_BYTES = (size_t)M_DIM * KCAT * sizeof(bf16_t);  // 32 MiB
  bf16_t* acat = (bf16_t*)d_ws;
  bf16_t* wcat = (bf16_t*)((char*)d_ws + ACAT_BYTES);

  hipLaunchKernelGGL(convert_acat, dim3(8192), dim3(256), 0, stream, inputs, Z,
                     acat);
  hipLaunchKernelGGL(transpose_wcat, dim3(N_DIM / 64, K_DIM / 64, 2), dim3(256),
                     0, stream, fwd_w, rec_w, wcat);

  (void)hipFuncSetAttribute(reinterpret_cast<const void*>(lif_gemm_8p),
                            hipFuncAttributeMaxDynamicSharedMemorySize,
                            LDS_BYTES);
  hipLaunchKernelGGL(lif_gemm_8p, dim3((M_DIM / BM) * (N_DIM / BN)), dim3(512),
                     LDS_BYTES, stream, acat, wcat, I, V, Z, outZ, outI, outV);
}